// Round 2
// baseline (150.670 us; speedup 1.0000x reference)
//
#include <hip/hip_runtime.h>

// out = A @ x, A sparse COO (rows sorted), E=800000, N=50000, D=128.
// Edge-parallel segmented reduction with register prefetch:
//  - each wave owns a contiguous edge range; lane l owns feature dims {2l,2l+1}
//  - per chunk of 8 edges: issue all 8 x-row gathers first (8 outstanding
//    loads -> MLP), then accumulate with lazy atomic flush on row change.

#define D_FEAT 128
#define TOTAL_WAVES 8192
#define WAVES_PER_BLOCK 4
#define BLOCK_THREADS (WAVES_PER_BLOCK * 64)
#define PF 8  // prefetch depth (edges per chunk)

__device__ __forceinline__ float bcast_f(float v, int j) {
    return __int_as_float(__builtin_amdgcn_readlane(__float_as_int(v), j));
}

__global__ __launch_bounds__(BLOCK_THREADS) void agg_kernel(
    const float* __restrict__ x, const float* __restrict__ vals,
    const int* __restrict__ rows, const int* __restrict__ cols,
    float* __restrict__ out, int n_edges, int epw) {
    const int wave = blockIdx.x * WAVES_PER_BLOCK + (threadIdx.x >> 6);
    const int lane = threadIdx.x & 63;

    const int start = wave * epw;
    if (start >= n_edges) return;
    int end = start + epw;
    if (end > n_edges) end = n_edges;

    const float2* __restrict__ x2 = (const float2*)x;

    float2 acc = make_float2(0.f, 0.f);
    int cur_row = rows[start];  // wave-uniform

    for (int e0 = start; e0 < end; e0 += 64) {
        const int nb = min(end - e0, 64);
        int   myc = 0;
        int   myr = 0;
        float myv = 0.f;
        if (lane < nb) {
            myc = cols[e0 + lane];
            myr = rows[e0 + lane];
            myv = vals[e0 + lane];
        }
        for (int j0 = 0; j0 < nb; j0 += PF) {
            const int m = min(nb - j0, PF);
            float2 xv[PF];
            int    rj[PF];
            float  vj[PF];
            // Phase 1: issue all gathers (independent -> PF outstanding loads)
#pragma unroll
            for (int t = 0; t < PF; ++t) {
                if (t < m) {
                    const int cj = __builtin_amdgcn_readlane(myc, j0 + t);
                    rj[t] = __builtin_amdgcn_readlane(myr, j0 + t);
                    vj[t] = bcast_f(myv, j0 + t);
                    xv[t] = x2[(size_t)cj * (D_FEAT / 2) + lane];
                }
            }
            // Phase 2: accumulate, flushing on (rare, wave-uniform) row change
#pragma unroll
            for (int t = 0; t < PF; ++t) {
                if (t < m) {
                    if (rj[t] != cur_row) {
                        float* o = out + (size_t)cur_row * D_FEAT + 2 * lane;
                        atomicAdd(o,     acc.x);
                        atomicAdd(o + 1, acc.y);
                        acc.x = 0.f; acc.y = 0.f;
                        cur_row = rj[t];
                    }
                    acc.x += vj[t] * xv[t].x;
                    acc.y += vj[t] * xv[t].y;
                }
            }
        }
    }
    float* o = out + (size_t)cur_row * D_FEAT + 2 * lane;
    atomicAdd(o,     acc.x);
    atomicAdd(o + 1, acc.y);
}

extern "C" void kernel_launch(void* const* d_in, const int* in_sizes, int n_in,
                              void* d_out, int out_size, void* d_ws, size_t ws_size,
                              hipStream_t stream) {
    const float* x    = (const float*)d_in[0];
    const float* vals = (const float*)d_in[1];
    const int*   rows = (const int*)d_in[2];
    const int*   cols = (const int*)d_in[3];
    float*       out  = (float*)d_out;

    const int n_edges = in_sizes[1];

    // Zero output (harness poisons it with 0xAA before every timed launch).
    hipMemsetAsync(d_out, 0, (size_t)out_size * sizeof(float), stream);

    const int epw = (n_edges + TOTAL_WAVES - 1) / TOTAL_WAVES;  // edges per wave
    const int blocks = TOTAL_WAVES / WAVES_PER_BLOCK;
    agg_kernel<<<blocks, BLOCK_THREADS, 0, stream>>>(x, vals, rows, cols, out,
                                                     n_edges, epw);
}

// Round 3
// 142.332 us; speedup vs baseline: 1.0586x; 1.0586x over previous
//
#include <hip/hip_runtime.h>

// out = A @ x, A sparse COO (rows sorted), E=800000, N=50000, D=128.
// Edge-parallel segmented reduction. Each wave owns a contiguous edge range;
// lane l owns feature dims {2l,2l+1}. Because rows are sorted, only the
// FIRST and LAST row of a wave's range can be shared with a neighboring
// wave -> those flush with atomicAdd; strictly-interior rows have a single
// writer and flush with a plain float2 store (memset supplies zeros for
// untouched rows).

#define D_FEAT 128
#define TOTAL_WAVES 8192
#define WAVES_PER_BLOCK 4
#define BLOCK_THREADS (WAVES_PER_BLOCK * 64)
#define PF 8  // prefetch depth (edges per chunk)

__device__ __forceinline__ float bcast_f(float v, int j) {
    return __int_as_float(__builtin_amdgcn_readlane(__float_as_int(v), j));
}

__global__ __launch_bounds__(BLOCK_THREADS) void agg_kernel(
    const float* __restrict__ x, const float* __restrict__ vals,
    const int* __restrict__ rows, const int* __restrict__ cols,
    float* __restrict__ out, int n_edges, int epw) {
    const int wave = blockIdx.x * WAVES_PER_BLOCK + (threadIdx.x >> 6);
    const int lane = threadIdx.x & 63;

    const int start = wave * epw;
    if (start >= n_edges) return;
    int end = start + epw;
    if (end > n_edges) end = n_edges;

    const float2* __restrict__ x2 = (const float2*)x;

    // Boundary rows: possibly shared with the previous/next wave.
    const int first_row = rows[start];    // wave-uniform broadcast load
    const int last_row  = rows[end - 1];  // wave-uniform broadcast load

    float2 acc = make_float2(0.f, 0.f);
    int cur_row = first_row;

    for (int e0 = start; e0 < end; e0 += 64) {
        const int nb = min(end - e0, 64);
        int   myc = 0;
        int   myr = 0;
        float myv = 0.f;
        if (lane < nb) {
            myc = cols[e0 + lane];
            myr = rows[e0 + lane];
            myv = vals[e0 + lane];
        }
        for (int j0 = 0; j0 < nb; j0 += PF) {
            const int m = min(nb - j0, PF);
            float2 xv[PF];
            int    rj[PF];
            float  vj[PF];
            // Phase 1: issue all gathers (independent -> PF outstanding loads)
#pragma unroll
            for (int t = 0; t < PF; ++t) {
                if (t < m) {
                    const int cj = __builtin_amdgcn_readlane(myc, j0 + t);
                    rj[t] = __builtin_amdgcn_readlane(myr, j0 + t);
                    vj[t] = bcast_f(myv, j0 + t);
                    xv[t] = x2[(size_t)cj * (D_FEAT / 2) + lane];
                }
            }
            // Phase 2: accumulate, flushing on (rare, wave-uniform) row change
#pragma unroll
            for (int t = 0; t < PF; ++t) {
                if (t < m) {
                    if (rj[t] != cur_row) {
                        float* o = out + (size_t)cur_row * D_FEAT + 2 * lane;
                        if (cur_row == first_row || cur_row == last_row) {
                            atomicAdd(o,     acc.x);
                            atomicAdd(o + 1, acc.y);
                        } else {
                            *(float2*)o = acc;  // sole writer: full sum
                        }
                        acc.x = 0.f; acc.y = 0.f;
                        cur_row = rj[t];
                    }
                    acc.x += vj[t] * xv[t].x;
                    acc.y += vj[t] * xv[t].y;
                }
            }
        }
    }
    // Final flush: cur_row == last_row (or first_row), always atomic.
    float* o = out + (size_t)cur_row * D_FEAT + 2 * lane;
    atomicAdd(o,     acc.x);
    atomicAdd(o + 1, acc.y);
}

extern "C" void kernel_launch(void* const* d_in, const int* in_sizes, int n_in,
                              void* d_out, int out_size, void* d_ws, size_t ws_size,
                              hipStream_t stream) {
    const float* x    = (const float*)d_in[0];
    const float* vals = (const float*)d_in[1];
    const int*   rows = (const int*)d_in[2];
    const int*   cols = (const int*)d_in[3];
    float*       out  = (float*)d_out;

    const int n_edges = in_sizes[1];

    // Zero output (harness poisons it with 0xAA before every timed launch).
    hipMemsetAsync(d_out, 0, (size_t)out_size * sizeof(float), stream);

    const int epw = (n_edges + TOTAL_WAVES - 1) / TOTAL_WAVES;  // edges per wave
    const int blocks = TOTAL_WAVES / WAVES_PER_BLOCK;
    agg_kernel<<<blocks, BLOCK_THREADS, 0, stream>>>(x, vals, rows, cols, out,
                                                     n_edges, epw);
}